// Round 6
// baseline (14.939 us; speedup 1.0000x reference)
//
#include <hip/hip_runtime.h>
#include <hip/hip_bf16.h>

// Problem: N=32, T=5, V=64, F=512, t_mid = 2
// xm = x[:, 2, :, :]                         (32, 64, 512)
// tmpS[n,i,j] = exp( sum_f |xm[n,i,f]-xm[n,j,f]| * a[f] )   (symmetric in i,j)
// colsum[n,i] = sum_k tmpS[n,k,i] == sum_k tmpS[n,i,k]  (symmetry -> row-local)
// S[n,i,j] = tmpS[n,i,j] / colsum[n,i]
//
// R6: IB=4 x JB=4 tiling, 512-thread blocks (32 f-parts x 16 jg), 4 k-iters.
// __launch_bounds__(512,4) caps VGPR at 128 so 2 blocks/CU co-reside ->
// 4 waves/SIMD TLP (R3/R5 hypothesis: reg blow-up collapsed occupancy).

#define NN 32
#define TT 5
#define VV 64
#define FF 512
#define TMID 2
#define IB 4            // i-rows per block (LDS-staged)
#define RSTRIDE 65      // padded stride for red[]

__global__ __launch_bounds__(512, 4) void pairsim_kernel(
    const float* __restrict__ x, const float* __restrict__ a,
    float* __restrict__ out) {
  const int b = blockIdx.x;        // 0 .. NN*(VV/IB)-1 = 511
  const int n = b >> 4;
  const int i0 = (b & 15) * IB;
  const int t = threadIdx.x;       // 0 .. 511

  __shared__ float xi[IB * FF];        // 8 KB
  __shared__ float av[FF];             // 2 KB
  __shared__ float red[IB * RSTRIDE];  // ~1 KB

  const float* xm = x + ((size_t)n * TT + TMID) * (size_t)VV * FF;

  // Stage xi rows (contiguous 8 KB) + a, float4-coalesced.
  {
    const float4* src_xi = reinterpret_cast<const float4*>(xm + (size_t)i0 * FF);
    const float4* src_a  = reinterpret_cast<const float4*>(a);
    float4* dst_xi = reinterpret_cast<float4*>(xi);
    float4* dst_a  = reinterpret_cast<float4*>(av);
    for (int idx = t; idx < (IB * FF / 4) + (FF / 4); idx += 512) {
      if (idx < IB * FF / 4) dst_xi[idx] = src_xi[idx];
      else                   dst_a[idx - IB * FF / 4] = src_a[idx - IB * FF / 4];
    }
  }
  __syncthreads();

  const int part = t & 31;         // f-partition 0..31
  const int jg   = t >> 5;         // 0..15; owns j = jg + 16*js
  const float* xj0 = xm + (size_t)(jg     ) * FF;
  const float* xj1 = xm + (size_t)(jg + 16) * FF;
  const float* xj2 = xm + (size_t)(jg + 32) * FF;
  const float* xj3 = xm + (size_t)(jg + 48) * FF;

  float acc[4][4];                 // [i][js] — all indices compile-time
#pragma unroll
  for (int i = 0; i < 4; ++i)
#pragma unroll
    for (int js = 0; js < 4; ++js) acc[i][js] = 0.f;

#pragma unroll
  for (int k = 0; k < 4; ++k) {
    const int f = k * 128 + part * 4;  // 32-lane part-group covers 512B contig
    float4 va = *reinterpret_cast<const float4*>(av + f);
    float4 v0 = *reinterpret_cast<const float4*>(xi + 0 * FF + f);
    float4 v1 = *reinterpret_cast<const float4*>(xi + 1 * FF + f);
    float4 v2 = *reinterpret_cast<const float4*>(xi + 2 * FF + f);
    float4 v3 = *reinterpret_cast<const float4*>(xi + 3 * FF + f);

    // Each vj is loaded right before its FMA block -> short live range.
#define JBLOCK(JS, XJ)                                          \
    {                                                           \
      float4 vj = *reinterpret_cast<const float4*>(XJ + f);     \
      acc[0][JS] = fmaf(fabsf(v0.x - vj.x), va.x, acc[0][JS]);  \
      acc[0][JS] = fmaf(fabsf(v0.y - vj.y), va.y, acc[0][JS]);  \
      acc[0][JS] = fmaf(fabsf(v0.z - vj.z), va.z, acc[0][JS]);  \
      acc[0][JS] = fmaf(fabsf(v0.w - vj.w), va.w, acc[0][JS]);  \
      acc[1][JS] = fmaf(fabsf(v1.x - vj.x), va.x, acc[1][JS]);  \
      acc[1][JS] = fmaf(fabsf(v1.y - vj.y), va.y, acc[1][JS]);  \
      acc[1][JS] = fmaf(fabsf(v1.z - vj.z), va.z, acc[1][JS]);  \
      acc[1][JS] = fmaf(fabsf(v1.w - vj.w), va.w, acc[1][JS]);  \
      acc[2][JS] = fmaf(fabsf(v2.x - vj.x), va.x, acc[2][JS]);  \
      acc[2][JS] = fmaf(fabsf(v2.y - vj.y), va.y, acc[2][JS]);  \
      acc[2][JS] = fmaf(fabsf(v2.z - vj.z), va.z, acc[2][JS]);  \
      acc[2][JS] = fmaf(fabsf(v2.w - vj.w), va.w, acc[2][JS]);  \
      acc[3][JS] = fmaf(fabsf(v3.x - vj.x), va.x, acc[3][JS]);  \
      acc[3][JS] = fmaf(fabsf(v3.y - vj.y), va.y, acc[3][JS]);  \
      acc[3][JS] = fmaf(fabsf(v3.z - vj.z), va.z, acc[3][JS]);  \
      acc[3][JS] = fmaf(fabsf(v3.w - vj.w), va.w, acc[3][JS]);  \
    }

    JBLOCK(0, xj0)
    JBLOCK(1, xj1)
    JBLOCK(2, xj2)
    JBLOCK(3, xj3)
#undef JBLOCK
  }

  // Fold the 32 f-partitions within each 32-lane part group.
#pragma unroll
  for (int i = 0; i < 4; ++i)
#pragma unroll
    for (int js = 0; js < 4; ++js) {
      float v = acc[i][js];
      v += __shfl_xor(v, 1);
      v += __shfl_xor(v, 2);
      v += __shfl_xor(v, 4);
      v += __shfl_xor(v, 8);
      v += __shfl_xor(v, 16);
      acc[i][js] = v;
    }

  // Threads with part<16 each write one exp value: (ri = part&3, rj = part>>2).
  if (part < 16) {
    const int ri = part & 3;
    const int rj = part >> 2;
    float pick = 0.f;
#pragma unroll
    for (int i = 0; i < 4; ++i)
#pragma unroll
      for (int js = 0; js < 4; ++js)
        if (ri == i && rj == js) pick = acc[i][js];
    red[ri * RSTRIDE + jg + (rj << 4)] = __expf(pick);
  }
  __syncthreads();

  // First 4 waves: one per i-row, butterfly row-sum, coalesced 256B row write.
  if (t < 256) {
    const int w = t >> 6;          // i-row
    const int lane = t & 63;       // j
    float v = red[w * RSTRIDE + lane];
    float s = v;
#pragma unroll
    for (int o = 1; o < 64; o <<= 1) s += __shfl_xor(s, o);
    out[(((size_t)n * VV + i0 + w) << 6) + lane] = v / s;
  }
}

extern "C" void kernel_launch(void* const* d_in, const int* in_sizes, int n_in,
                              void* d_out, int out_size, void* d_ws, size_t ws_size,
                              hipStream_t stream) {
  const float* x = (const float*)d_in[0];
  const float* a = (const float*)d_in[1];
  float* out = (float*)d_out;
  pairsim_kernel<<<NN * (VV / IB), 512, 0, stream>>>(x, a, out);
}

// Round 7
// 10.947 us; speedup vs baseline: 1.3647x; 1.3647x over previous
//
#include <hip/hip_runtime.h>
#include <hip/hip_bf16.h>

// Problem: N=32, T=5, V=64, F=512, t_mid = 2
// xm = x[:, 2, :, :]                         (32, 64, 512)
// tmpS[n,i,j] = exp( sum_f |xm[n,i,f]-xm[n,j,f]| * a[f] )   (symmetric in i,j)
// colsum[n,i] = sum_k tmpS[n,k,i] == sum_k tmpS[n,i,k]  (symmetry -> row-local)
// S[n,i,j] = tmpS[n,i,j] / colsum[n,i]
//
// R7 = R2 (best measured: 12.0 us) + two minimal deltas:
//  (1) bijective XCD swizzle: same-n blocks land on the same XCD ->
//      per-XCD L2 cold-fill drops 4 MB -> 512 KB (T1 mechanism).
//  (2) __expf in the tail.
// Everything else byte-identical to R2's structure: 256 thr, part=t&3,
// j=t>>2, 32 fully-unrolled k-iters, broadcast LDS reads for vi/va.

#define NN 32
#define TT 5
#define VV 64
#define FF 512
#define TMID 2
#define IB 4            // i-rows per block

__global__ __launch_bounds__(256) void pairsim_kernel(
    const float* __restrict__ x, const float* __restrict__ a,
    float* __restrict__ out) {
  // XCD-aware bijective swizzle (512 blocks, 8 XCDs, 64 blocks/XCD).
  // Dispatch round-robins blockIdx across XCDs; this maps 64 consecutive
  // logical b (4 n-panels) onto one XCD.
  const int b = ((blockIdx.x & 7) << 6) | (blockIdx.x >> 3);
  const int n = b >> 4;            // b / 16
  const int i0 = (b & 15) * IB;    // first i-row of this block
  const int t = threadIdx.x;       // 0 .. 255

  __shared__ float xi[IB * FF];    // 4 rows of xm[n] (8 KB)
  __shared__ float av[FF];         // weight vector a (2 KB)
  __shared__ float red[IB][VV];    // exp values per (i,j)

  const float* xm = x + ((size_t)n * TT + TMID) * (size_t)VV * FF;

  // Stage xi rows (contiguous 8 KB) + a into LDS, float4-coalesced.
  {
    const float4* src_xi = reinterpret_cast<const float4*>(xm + (size_t)i0 * FF);
    const float4* src_a  = reinterpret_cast<const float4*>(a);
    float4* dst_xi = reinterpret_cast<float4*>(xi);
    float4* dst_a  = reinterpret_cast<float4*>(av);
    for (int idx = t; idx < (IB * FF / 4) + (FF / 4); idx += 256) {
      if (idx < IB * FF / 4) dst_xi[idx] = src_xi[idx];
      else                   dst_a[idx - IB * FF / 4] = src_a[idx - IB * FF / 4];
    }
  }
  __syncthreads();

  const int j = t >> 2;            // 0..63
  const int part = t & 3;          // 0..3
  const float* xj = xm + (size_t)j * FF;

  float acc0 = 0.f, acc1 = 0.f, acc2 = 0.f, acc3 = 0.f;
#pragma unroll
  for (int k = 0; k < 32; ++k) {
    const int f = k * 16 + part * 4;   // each 4-lane group covers contiguous 64B
    float4 vj = *reinterpret_cast<const float4*>(xj + f);
    float4 va = *reinterpret_cast<const float4*>(av + f);
    float4 v0 = *reinterpret_cast<const float4*>(xi + 0 * FF + f);
    float4 v1 = *reinterpret_cast<const float4*>(xi + 1 * FF + f);
    float4 v2 = *reinterpret_cast<const float4*>(xi + 2 * FF + f);
    float4 v3 = *reinterpret_cast<const float4*>(xi + 3 * FF + f);
    acc0 = fmaf(fabsf(v0.x - vj.x), va.x, acc0);
    acc0 = fmaf(fabsf(v0.y - vj.y), va.y, acc0);
    acc0 = fmaf(fabsf(v0.z - vj.z), va.z, acc0);
    acc0 = fmaf(fabsf(v0.w - vj.w), va.w, acc0);
    acc1 = fmaf(fabsf(v1.x - vj.x), va.x, acc1);
    acc1 = fmaf(fabsf(v1.y - vj.y), va.y, acc1);
    acc1 = fmaf(fabsf(v1.z - vj.z), va.z, acc1);
    acc1 = fmaf(fabsf(v1.w - vj.w), va.w, acc1);
    acc2 = fmaf(fabsf(v2.x - vj.x), va.x, acc2);
    acc2 = fmaf(fabsf(v2.y - vj.y), va.y, acc2);
    acc2 = fmaf(fabsf(v2.z - vj.z), va.z, acc2);
    acc2 = fmaf(fabsf(v2.w - vj.w), va.w, acc2);
    acc3 = fmaf(fabsf(v3.x - vj.x), va.x, acc3);
    acc3 = fmaf(fabsf(v3.y - vj.y), va.y, acc3);
    acc3 = fmaf(fabsf(v3.z - vj.z), va.z, acc3);
    acc3 = fmaf(fabsf(v3.w - vj.w), va.w, acc3);
  }
  // Fold the 4 f-partitions (lanes j*4 .. j*4+3).
  acc0 += __shfl_xor(acc0, 1); acc0 += __shfl_xor(acc0, 2);
  acc1 += __shfl_xor(acc1, 1); acc1 += __shfl_xor(acc1, 2);
  acc2 += __shfl_xor(acc2, 1); acc2 += __shfl_xor(acc2, 2);
  acc3 += __shfl_xor(acc3, 1); acc3 += __shfl_xor(acc3, 2);

  if (part == 0) {
    red[0][j] = __expf(acc0);
    red[1][j] = __expf(acc1);
    red[2][j] = __expf(acc2);
    red[3][j] = __expf(acc3);
  }
  __syncthreads();

  // 4 waves, one per i-row: butterfly row-sum, then coalesced 256B row write.
  {
    const int w = t >> 6;          // 0..3 -> i-row
    const int lane = t & 63;       // j
    float v = red[w][lane];
    float s = v;
#pragma unroll
    for (int o = 1; o < 64; o <<= 1) s += __shfl_xor(s, o);
    out[(((size_t)n * VV + i0 + w) << 6) + lane] = v / s;
  }
}

extern "C" void kernel_launch(void* const* d_in, const int* in_sizes, int n_in,
                              void* d_out, int out_size, void* d_ws, size_t ws_size,
                              hipStream_t stream) {
  const float* x = (const float*)d_in[0];
  const float* a = (const float*)d_in[1];
  float* out = (float*)d_out;
  pairsim_kernel<<<NN * (VV / IB), 256, 0, stream>>>(x, a, out);
}